// Round 15
// baseline (31.544 us; speedup 1.0000x reference)
//
#include <hip/hip_runtime.h>

#define N_NODES 30000
#define C 128
#define BM 128
#define NBLK 235   // ceil(30000/128)

typedef __attribute__((ext_vector_type(8))) short bf16x8;
typedef __attribute__((ext_vector_type(4))) float f32x4;

// ws layout:
//   shorts [0, 32768)        : B~t FRAGMENT-MAJOR bf16 [set][frag(32)][lane(64)][8]
//                              frag = (wj*4+ks)*2+nt ; lane = lk*16+l15
//                              B~ = wv^T (wp[:,:C] + wp[:,C:])^T  (masks==1 collapse, r12)
//   float 16384 + set*128    : cvS f32 [set][128] = cv_A + cv_B + bp
#define CVS_OFF_F(set) (16384 + (set) * 128)

__device__ __forceinline__ unsigned short f2bf(float f) {
  union { float f; unsigned int u; } v; v.f = f;
  unsigned int r = v.u + 0x7FFF + ((v.u >> 16) & 1);  // RNE
  return (unsigned short)(r >> 16);
}

// ---------------------------------------------------------------------------
// K1: prep. B~t fragment-major + cvS. grid (128, 2), block 128. (r14, verified)
// ---------------------------------------------------------------------------
__global__ void prep_kernel(const float* __restrict__ wv1, const float* __restrict__ bv1,
                            const float* __restrict__ wp1, const float* __restrict__ bp1,
                            const float* __restrict__ wv2, const float* __restrict__ bv2,
                            const float* __restrict__ wp2, const float* __restrict__ bp2,
                            float* __restrict__ ws) {
  const int k = blockIdx.x;   // GEMM k index 0..127
  const int set = blockIdx.y;
  const float* wv = set ? wv2 : wv1;
  const float* bv = set ? bv2 : bv1;
  const float* wp = set ? wp2 : wp1;
  const float* bp = set ? bp2 : bp1;

  __shared__ float wvcol[C];
  const int t = threadIdx.x;   // 0..127
  wvcol[t] = wv[t * C + k];
  __syncthreads();

  const int j = t;  // output col 0..127
  const float* wprow = wp + j * (2 * C);
  float s = 0.f;
#pragma unroll 4
  for (int c = 0; c < C; ++c) s += wvcol[c] * (wprow[c] + wprow[C + c]);

  const int wj  = j >> 5;
  const int nt  = (j >> 4) & 1;
  const int l15 = j & 15;
  const int ks  = k >> 5;
  const int lk  = (k >> 3) & 3;
  const int jj  = k & 7;
  const int frag = (wj * 4 + ks) * 2 + nt;
  const int lane = lk * 16 + l15;
  ((unsigned short*)ws)[set * 16384 + frag * 512 + lane * 8 + jj] = f2bf(s);

  if (k == 0) {
    float s2 = 0.f;
#pragma unroll 4
    for (int c = 0; c < C; ++c) s2 += bv[c] * (wprow[c] + wprow[C + c]);
    ws[CVS_OFF_F(set) + j] = s2 + bp[j];
  }
}

// ---------------------------------------------------------------------------
// K2: single-generation streaming main. BM=128, 512 thr (8 waves = 2wm x 4wj),
// grid (235,2)=470 blocks -> ALL co-resident (2 blocks/CU, 64 KB LDS each).
//   A: f32 staged via global_load_lds (width 16, zero VGPR round-trip), LDS
//      linear dest + pre-swizzled global source (XOR (r&7)<<4 on 16B chunks);
//      frag reads apply the same XOR -> 2-way bank aliasing (free), f2bf at read.
//   B~: 8 frags/wave in 32 VGPR (1KB coalesced L2 loads).
//   MFMA swapped: lane owns row i, 4 consecutive jj. out = acc + cvS.
// ---------------------------------------------------------------------------
__global__ __launch_bounds__(512, 4) void main_kernel(
    const float* __restrict__ feat1, const float* __restrict__ feat2,
    const float* __restrict__ ws, float* __restrict__ out) {
  const int set = blockIdx.y;
  const float* feat = set ? feat2 : feat1;
  const unsigned short* Btf = (const unsigned short*)ws + (size_t)set * 16384;
  const float* cvS = ws + CVS_OFF_F(set);
  float* outp = out + (size_t)set * N_NODES * C;

  __shared__ float feat_s[BM * C];  // 64 KB, swizzled f32

  const int i0 = blockIdx.x * BM;
  const int tid = threadIdx.x;
  const int wave = tid >> 6;
  const int lane = tid & 63;
  const int wm = wave >> 2;    // 0..1 -> rows [wm*64, +64)
  const int wj = wave & 3;     // 0..3 -> cols [wj*32, +32)
  const int l15 = lane & 15;
  const int lk  = lane >> 4;

  // ---- (1) stage 128 rows x 512 B via global_load_lds, source pre-swizzled ----
#pragma unroll
  for (int p = 0; p < 8; ++p) {
    const int idx = tid + 512 * p;     // 0..4095 (16B chunks)
    const int r = idx >> 5;            // row 0..127
    const int q = idx & 31;            // chunk in row
    int gi = i0 + r;
    if (gi >= N_NODES) gi = N_NODES - 1;
    const int srcb = (q * 16) ^ ((r & 7) << 4);   // inverse of read-side XOR
    const char* src = (const char*)(feat + (size_t)gi * C) + srcb;
    char* dst = (char*)feat_s + idx * 16;         // linear: wave base + lane*16
    __builtin_amdgcn_global_load_lds(
        (const __attribute__((address_space(1))) void*)src,
        (__attribute__((address_space(3))) void*)dst, 16, 0, 0);
  }

  // ---- (2) B~ frags (32 VGPR) + col constants; drained by the barrier ----
  const unsigned short* bfrag = Btf + (size_t)lane * 8;
  bf16x8 breg[4][2];  // [ks][nt]
#pragma unroll
  for (int ks = 0; ks < 4; ++ks)
#pragma unroll
    for (int nt = 0; nt < 2; ++nt)
      breg[ks][nt] = *reinterpret_cast<const bf16x8*>(
          bfrag + (size_t)((wj * 4 + ks) * 2 + nt) * 512);

  const int jjb = wj * 32 + lk * 4;
  float4 cvS4[2];
#pragma unroll
  for (int nt = 0; nt < 2; ++nt)
    cvS4[nt] = *reinterpret_cast<const float4*>(cvS + jjb + nt * 16);

  __syncthreads();  // vmcnt(0) drain (gload_lds + breg) + barrier

  // ---- (3) compute: 4 mt x 4 ks, cvt at read ----
  f32x4 acc[4][2] = {};  // [mt][nt]

#pragma unroll
  for (int ks = 0; ks < 4; ++ks) {
#pragma unroll
    for (int mt = 0; mt < 4; ++mt) {
      const int row = wm * 64 + mt * 16 + l15;
      const int Xr = (row & 7) << 4;
      const char* base = (const char*)feat_s + row * 512;
      const int b1 = ks * 128 + lk * 32;
      const float4 v0 = *reinterpret_cast<const float4*>(base + (b1 ^ Xr));
      const float4 v1 = *reinterpret_cast<const float4*>(base + ((b1 + 16) ^ Xr));
      bf16x8 a;
      a[0] = (short)f2bf(v0.x); a[1] = (short)f2bf(v0.y);
      a[2] = (short)f2bf(v0.z); a[3] = (short)f2bf(v0.w);
      a[4] = (short)f2bf(v1.x); a[5] = (short)f2bf(v1.y);
      a[6] = (short)f2bf(v1.z); a[7] = (short)f2bf(v1.w);
#pragma unroll
      for (int nt = 0; nt < 2; ++nt)
        acc[mt][nt] = __builtin_amdgcn_mfma_f32_16x16x32_bf16(
            breg[ks][nt], a, acc[mt][nt], 0, 0, 0);  // swapped: lane owns row i
    }
  }

  // ---- (4) epilogue: i = i0 + wm*64 + mt*16 + l15 ; jj4 = jjb + nt*16 ----
#pragma unroll
  for (int mt = 0; mt < 4; ++mt) {
    const int i = i0 + wm * 64 + mt * 16 + l15;
    if (i >= N_NODES) continue;
#pragma unroll
    for (int nt = 0; nt < 2; ++nt) {
      float4 o;
      o.x = acc[mt][nt][0] + cvS4[nt].x;
      o.y = acc[mt][nt][1] + cvS4[nt].y;
      o.z = acc[mt][nt][2] + cvS4[nt].z;
      o.w = acc[mt][nt][3] + cvS4[nt].w;
      *reinterpret_cast<float4*>(outp + (size_t)i * C + jjb + nt * 16) = o;
    }
  }
}

// ---------------------------------------------------------------------------
extern "C" void kernel_launch(void* const* d_in, const int* in_sizes, int n_in,
                              void* d_out, int out_size, void* d_ws, size_t ws_size,
                              hipStream_t stream) {
  const float* feat1 = (const float*)d_in[0];
  const float* feat2 = (const float*)d_in[2];
  const float* wv1 = (const float*)d_in[20];
  const float* bv1 = (const float*)d_in[21];
  const float* wv2 = (const float*)d_in[22];
  const float* bv2 = (const float*)d_in[23];
  const float* wp1 = (const float*)d_in[24];
  const float* bp1 = (const float*)d_in[25];
  const float* wp2 = (const float*)d_in[26];
  const float* bp2 = (const float*)d_in[27];

  float* ws = (float*)d_ws;
  float* out = (float*)d_out;

  prep_kernel<<<dim3(128, 2), 128, 0, stream>>>(
      wv1, bv1, wp1, bp1, wv2, bv2, wp2, bp2, ws);
  main_kernel<<<dim3(NBLK, 2), 512, 0, stream>>>(feat1, feat2, ws, out);
}